// Round 5
// baseline (295.397 us; speedup 1.0000x reference)
//
#include <hip/hip_runtime.h>

#define TS 512  // timesteps
#define DD 64   // input dim
#define HH 32   // hidden dim
#define NG 96   // 3*HH gates

typedef _Float16 half2v __attribute__((ext_vector_type(2)));

__device__ __forceinline__ float fdot2(half2v a, half2v b, float c) {
#if __has_builtin(__builtin_amdgcn_fdot2)
    return __builtin_amdgcn_fdot2(a, b, c, false);
#else
    return fmaf((float)a[0], (float)b[0], fmaf((float)a[1], (float)b[1], c));
#endif
}

__device__ __forceinline__ float fast_sigmoid(float a) {
    return __builtin_amdgcn_rcpf(1.0f + __expf(-a));
}

// =====================================================================
// Kernel 1: xg[b][t][g] = sum_d x[b][t][d] * Wih[g][d] + bih[g]  (fp16)
// 1024 blocks x 192 threads (3 waves). Wave w owns gates [32w, 32w+32).
// lane = j*32 + g': j = k-half (32 of 64 d's), per-lane 16 fdot2/row,
// halves combined with shfl_xor(32). x staged via per-wave LDS pipeline.
// =====================================================================
__global__ __launch_bounds__(192, 1) void xg_gemm(
    const float* __restrict__ x,
    const float* __restrict__ Wih,
    const float* __restrict__ bih,
    _Float16* __restrict__ xg)
{
    __shared__ __align__(16) _Float16 xsw[3][4][DD];  // per-wave rotating x rows

    const int b    = blockIdx.x;
    const int tid  = threadIdx.x;
    const int w    = tid >> 6;        // wave 0..2
    const int lane = tid & 63;
    const int j    = lane >> 5;       // k-half
    const int g    = w * 32 + (lane & 31);  // gate 0..95

    // this lane's W row-half: 16 packed half2 regs
    half2v wg[16];
    {
        const float4* pw = reinterpret_cast<const float4*>(Wih + g * DD + j * 32);
#pragma unroll
        for (int k = 0; k < 8; ++k) {
            float4 a = pw[k];
            wg[2*k]   = half2v{(_Float16)a.x, (_Float16)a.y};
            wg[2*k+1] = half2v{(_Float16)a.z, (_Float16)a.w};
        }
    }
    const float bg = bih[g];

    const float* xr = x + (size_t)b * TS * DD;
    _Float16* og = xg + (size_t)b * TS * NG;

    // prologue: stage rows 0..2, keep rows 3..5 in flight
    float q0 = xr[0*DD + lane];
    float q1 = xr[1*DD + lane];
    float q2 = xr[2*DD + lane];
    float ra = xr[3*DD + lane];
    float rb = xr[4*DD + lane];
    float rc = xr[5*DD + lane];
    xsw[w][0][lane] = (_Float16)q0;
    xsw[w][1][lane] = (_Float16)q1;
    xsw[w][2][lane] = (_Float16)q2;
    __builtin_amdgcn_wave_barrier();

    for (int t = 0; t < TS; ++t) {
        xsw[w][(t + 3) & 3][lane] = (_Float16)ra;
        ra = rb; rb = rc;
        int tf = t + 6; if (tf > TS - 1) tf = TS - 1;
        rc = xr[tf * DD + lane];
        __builtin_amdgcn_wave_barrier();

        const uint4* xp = reinterpret_cast<const uint4*>(&xsw[w][t & 3][j * 32]);
        float a0 = 0.f, a1 = 0.f;
#pragma unroll
        for (int k = 0; k < 4; ++k) {
            uint4 q = xp[k];
            a0 = fdot2(wg[4*k  ], __builtin_bit_cast(half2v, q.x), a0);
            a1 = fdot2(wg[4*k+1], __builtin_bit_cast(half2v, q.y), a1);
            a0 = fdot2(wg[4*k+2], __builtin_bit_cast(half2v, q.z), a0);
            a1 = fdot2(wg[4*k+3], __builtin_bit_cast(half2v, q.w), a1);
        }
        float acc = a0 + a1;
        acc += __shfl_xor(acc, 32);
        if (j == 0) og[t * NG + g] = (_Float16)(acc + bg);
    }
}

// =====================================================================
// Kernel 2: recurrence. One wave per batch. lane = s*32+h.
// xg streamed from ws via 3-deep register prefetch (3 scalar fp16/step);
// only W_hh (24 packed regs) held resident -> no spill pressure.
// =====================================================================
__global__ __launch_bounds__(64, 1) void gru_rec(
    const _Float16* __restrict__ xg,
    const float* __restrict__ Whh,
    const float* __restrict__ bhh,
    const float* __restrict__ Wfc,
    const float* __restrict__ bfc,
    float* __restrict__ out)
{
    __shared__ __align__(16) _Float16 hs16[HH];

    const int b    = blockIdx.x;
    const int lane = threadIdx.x;
    const int s    = lane >> 5;
    const int h    = lane & 31;

    // W_hh rows (r,z,n), this lane's j-half: 24 packed regs
    half2v ur2[8], uz2[8], un2[8];
    {
        const float4* pr = reinterpret_cast<const float4*>(Whh + (0*HH + h)*HH + s*16);
        const float4* pz = reinterpret_cast<const float4*>(Whh + (1*HH + h)*HH + s*16);
        const float4* pn = reinterpret_cast<const float4*>(Whh + (2*HH + h)*HH + s*16);
#pragma unroll
        for (int k = 0; k < 4; ++k) {
            float4 a = pr[k];
            ur2[2*k]   = half2v{(_Float16)a.x, (_Float16)a.y};
            ur2[2*k+1] = half2v{(_Float16)a.z, (_Float16)a.w};
            float4 c = pz[k];
            uz2[2*k]   = half2v{(_Float16)c.x, (_Float16)c.y};
            uz2[2*k+1] = half2v{(_Float16)c.z, (_Float16)c.w};
            float4 e = pn[k];
            un2[2*k]   = half2v{(_Float16)e.x, (_Float16)e.y};
            un2[2*k+1] = half2v{(_Float16)e.z, (_Float16)e.w};
        }
    }

    const float cr  = bhh[h];
    const float cz  = bhh[HH + h];
    const float cn  = bhh[2*HH + h];
    const float wfc = Wfc[h];
    const float bf0 = bfc[0];

    const _Float16* xb = xg + (size_t)b * TS * NG;

    // rotating 3-deep prefetch of (xr,xz,xn) for this lane's h
    _Float16 xra = xb[0*NG + h],        xrb = xb[1*NG + h],        xrc = xb[2*NG + h];
    _Float16 xza = xb[0*NG + HH + h],   xzb = xb[1*NG + HH + h],   xzc = xb[2*NG + HH + h];
    _Float16 xna = xb[0*NG + 2*HH + h], xnb = xb[1*NG + 2*HH + h], xnc = xb[2*NG + 2*HH + h];

    float h_own = 0.f;
    half2v hv2[8];
#pragma unroll
    for (int k = 0; k < 8; ++k) hv2[k] = half2v{(_Float16)0.0f, (_Float16)0.0f};

    for (int t = 0; t < TS; ++t) {
        float xrv = (float)xra;
        float xzv = (float)xza;
        float xnv = (float)xna;
        xra = xrb; xrb = xrc;
        xza = xzb; xzb = xzc;
        xna = xnb; xnb = xnc;
        int tf = t + 3; if (tf > TS - 1) tf = TS - 1;
        xrc = xb[tf*NG + h];
        xzc = xb[tf*NG + HH + h];
        xnc = xb[tf*NG + 2*HH + h];

        // gh partial dots (this lane's 16 of 32 j's), 2 accumulators per gate
        float gr0 = 0.f, gr1 = 0.f, gz0 = 0.f, gz1 = 0.f, gn0 = 0.f, gn1 = 0.f;
#pragma unroll
        for (int k = 0; k < 4; ++k) {
            gr0 = fdot2(ur2[2*k  ], hv2[2*k  ], gr0);
            gr1 = fdot2(ur2[2*k+1], hv2[2*k+1], gr1);
            gz0 = fdot2(uz2[2*k  ], hv2[2*k  ], gz0);
            gz1 = fdot2(uz2[2*k+1], hv2[2*k+1], gz1);
            gn0 = fdot2(un2[2*k  ], hv2[2*k  ], gn0);
            gn1 = fdot2(un2[2*k+1], hv2[2*k+1], gn1);
        }
        float gr = gr0 + gr1;
        float gz = gz0 + gz1;
        float gn = gn0 + gn1;
        gr += __shfl_xor(gr, 32);
        gz += __shfl_xor(gz, 32);
        gn += __shfl_xor(gn, 32);

        // gates (redundant in both halves; identical results)
        float r = fast_sigmoid(xrv + cr + gr);
        float z = fast_sigmoid(xzv + cz + gz);
        float npre = xnv + r * (gn + cn);
        npre = fminf(fmaxf(npre, -30.f), 30.f);
        float e2 = __expf(-2.f * npre);
        float n = (1.f - e2) * __builtin_amdgcn_rcpf(1.f + e2);
        h_own = n + z * (h_own - n);

        // broadcast h (fp16) — wave-synchronous, block == 1 wave
        hs16[h] = (_Float16)h_own;
        __builtin_amdgcn_wave_barrier();
        {
            const uint4* hp = reinterpret_cast<const uint4*>(&hs16[s * 16]);
            uint4 q0 = hp[0];
            uint4 q1 = hp[1];
            hv2[0] = __builtin_bit_cast(half2v, q0.x);
            hv2[1] = __builtin_bit_cast(half2v, q0.y);
            hv2[2] = __builtin_bit_cast(half2v, q0.z);
            hv2[3] = __builtin_bit_cast(half2v, q0.w);
            hv2[4] = __builtin_bit_cast(half2v, q1.x);
            hv2[5] = __builtin_bit_cast(half2v, q1.y);
            hv2[6] = __builtin_bit_cast(half2v, q1.z);
            hv2[7] = __builtin_bit_cast(half2v, q1.w);
        }
    }

    // final fc: out[b] = dot(h, W_fc) + b_fc (each h counted twice -> x0.5)
    float v = h_own * wfc;
#pragma unroll
    for (int off = 32; off >= 1; off >>= 1) v += __shfl_xor(v, off);
    if (lane == 0) out[b] = 0.5f * v + bf0;
}

// =====================================================================
// Fallback (round-2 kernel, known-passing) if ws is too small.
// =====================================================================
__global__ __launch_bounds__(64, 1) void gru_fused_fb(
    const float* __restrict__ x,
    const float* __restrict__ Wih,
    const float* __restrict__ Whh,
    const float* __restrict__ bih,
    const float* __restrict__ bhh,
    const float* __restrict__ Wfc,
    const float* __restrict__ bfc,
    float* __restrict__ out)
{
    __shared__ __align__(16) _Float16 xs16[4][DD];
    __shared__ __align__(16) _Float16 hs16[HH];

    const int b    = blockIdx.x;
    const int lane = threadIdx.x;
    const int s    = lane >> 5;
    const int h    = lane & 31;

    half2v wr2[16], wz2[16], wn2[16];
    {
        const float4* pr = reinterpret_cast<const float4*>(Wih + (0*HH + h)*DD + s*32);
        const float4* pz = reinterpret_cast<const float4*>(Wih + (1*HH + h)*DD + s*32);
        const float4* pn = reinterpret_cast<const float4*>(Wih + (2*HH + h)*DD + s*32);
#pragma unroll
        for (int k = 0; k < 8; ++k) {
            float4 a = pr[k];
            wr2[2*k]   = half2v{(_Float16)a.x, (_Float16)a.y};
            wr2[2*k+1] = half2v{(_Float16)a.z, (_Float16)a.w};
            float4 c = pz[k];
            wz2[2*k]   = half2v{(_Float16)c.x, (_Float16)c.y};
            wz2[2*k+1] = half2v{(_Float16)c.z, (_Float16)c.w};
            float4 e = pn[k];
            wn2[2*k]   = half2v{(_Float16)e.x, (_Float16)e.y};
            wn2[2*k+1] = half2v{(_Float16)e.z, (_Float16)e.w};
        }
    }
    half2v ur2[8], uz2[8], un2[8];
    {
        const float4* pr = reinterpret_cast<const float4*>(Whh + (0*HH + h)*HH + s*16);
        const float4* pz = reinterpret_cast<const float4*>(Whh + (1*HH + h)*HH + s*16);
        const float4* pn = reinterpret_cast<const float4*>(Whh + (2*HH + h)*HH + s*16);
#pragma unroll
        for (int k = 0; k < 4; ++k) {
            float4 a = pr[k];
            ur2[2*k]   = half2v{(_Float16)a.x, (_Float16)a.y};
            ur2[2*k+1] = half2v{(_Float16)a.z, (_Float16)a.w};
            float4 c = pz[k];
            uz2[2*k]   = half2v{(_Float16)c.x, (_Float16)c.y};
            uz2[2*k+1] = half2v{(_Float16)c.z, (_Float16)c.w};
            float4 e = pn[k];
            un2[2*k]   = half2v{(_Float16)e.x, (_Float16)e.y};
            un2[2*k+1] = half2v{(_Float16)e.z, (_Float16)e.w};
        }
    }

    const float br  = bih[h]        + bhh[h];
    const float bz  = bih[HH + h]   + bhh[HH + h];
    const float bxn = bih[2*HH + h];
    const float bhn = bhh[2*HH + h];
    const float wfc = Wfc[h];
    const float bf0 = bfc[0];

    const float* xrow = x + (size_t)b * TS * DD;

    float p0 = xrow[0*DD + lane];
    float p1 = xrow[1*DD + lane];
    float p2 = xrow[2*DD + lane];
    float ra = xrow[3*DD + lane];
    float rb = xrow[4*DD + lane];
    float rc = xrow[5*DD + lane];
    xs16[0][lane] = (_Float16)p0;
    xs16[1][lane] = (_Float16)p1;
    xs16[2][lane] = (_Float16)p2;
    __builtin_amdgcn_wave_barrier();

    float h_own = 0.0f;
    half2v hv2[8];
#pragma unroll
    for (int k = 0; k < 8; ++k) hv2[k] = half2v{(_Float16)0.0f, (_Float16)0.0f};

    float ar, az, an;
    {
        const uint4* xp = reinterpret_cast<const uint4*>(&xs16[0][s * 32]);
        ar = 0.f; az = 0.f; an = 0.f;
#pragma unroll
        for (int k = 0; k < 4; ++k) {
            uint4 q = xp[k];
            half2v v0 = __builtin_bit_cast(half2v, q.x);
            half2v v1 = __builtin_bit_cast(half2v, q.y);
            half2v v2 = __builtin_bit_cast(half2v, q.z);
            half2v v3 = __builtin_bit_cast(half2v, q.w);
            ar = fdot2(wr2[4*k  ], v0, ar);  az = fdot2(wz2[4*k  ], v0, az);  an = fdot2(wn2[4*k  ], v0, an);
            ar = fdot2(wr2[4*k+1], v1, ar);  az = fdot2(wz2[4*k+1], v1, az);  an = fdot2(wn2[4*k+1], v1, an);
            ar = fdot2(wr2[4*k+2], v2, ar);  az = fdot2(wz2[4*k+2], v2, az);  an = fdot2(wn2[4*k+2], v2, an);
            ar = fdot2(wr2[4*k+3], v3, ar);  az = fdot2(wz2[4*k+3], v3, az);  an = fdot2(wn2[4*k+3], v3, an);
        }
    }

    for (int t = 0; t < TS; ++t) {
        xs16[(t + 3) & 3][lane] = (_Float16)ra;
        ra = rb; rb = rc;
        int tf = t + 6; if (tf > TS - 1) tf = TS - 1;
        rc = xrow[tf * DD + lane];

        float gr = 0.f, gz = 0.f, gn = 0.f;
#pragma unroll
        for (int k = 0; k < 8; ++k) {
            gr = fdot2(ur2[k], hv2[k], gr);
            gz = fdot2(uz2[k], hv2[k], gz);
            gn = fdot2(un2[k], hv2[k], gn);
        }

        float tr = ar + gr;  tr += __shfl_xor(tr, 32);
        float tz = az + gz;  tz += __shfl_xor(tz, 32);
        float txn = an + __shfl_xor(an, 32);
        float tgn = gn + __shfl_xor(gn, 32);

        float r = fast_sigmoid(tr + br);
        float z = fast_sigmoid(tz + bz);
        float npre = txn + bxn + r * (tgn + bhn);
        npre = fminf(fmaxf(npre, -30.f), 30.f);
        float e2 = __expf(-2.f * npre);
        float n = (1.f - e2) * __builtin_amdgcn_rcpf(1.f + e2);
        h_own = n + z * (h_own - n);

        hs16[h] = (_Float16)h_own;
        __builtin_amdgcn_wave_barrier();
        {
            const uint4* hp = reinterpret_cast<const uint4*>(&hs16[s * 16]);
            uint4 q0 = hp[0];
            uint4 q1 = hp[1];
            hv2[0] = __builtin_bit_cast(half2v, q0.x);
            hv2[1] = __builtin_bit_cast(half2v, q0.y);
            hv2[2] = __builtin_bit_cast(half2v, q0.z);
            hv2[3] = __builtin_bit_cast(half2v, q0.w);
            hv2[4] = __builtin_bit_cast(half2v, q1.x);
            hv2[5] = __builtin_bit_cast(half2v, q1.y);
            hv2[6] = __builtin_bit_cast(half2v, q1.z);
            hv2[7] = __builtin_bit_cast(half2v, q1.w);
        }

        if (t + 1 < TS) {
            const uint4* xp = reinterpret_cast<const uint4*>(&xs16[(t + 1) & 3][s * 32]);
            ar = 0.f; az = 0.f; an = 0.f;
#pragma unroll
            for (int k = 0; k < 4; ++k) {
                uint4 q = xp[k];
                half2v v0 = __builtin_bit_cast(half2v, q.x);
                half2v v1 = __builtin_bit_cast(half2v, q.y);
                half2v v2 = __builtin_bit_cast(half2v, q.z);
                half2v v3 = __builtin_bit_cast(half2v, q.w);
                ar = fdot2(wr2[4*k  ], v0, ar);  az = fdot2(wz2[4*k  ], v0, az);  an = fdot2(wn2[4*k  ], v0, an);
                ar = fdot2(wr2[4*k+1], v1, ar);  az = fdot2(wz2[4*k+1], v1, az);  an = fdot2(wn2[4*k+1], v1, an);
                ar = fdot2(wr2[4*k+2], v2, ar);  az = fdot2(wz2[4*k+2], v2, az);  an = fdot2(wn2[4*k+2], v2, an);
                ar = fdot2(wr2[4*k+3], v3, ar);  az = fdot2(wz2[4*k+3], v3, az);  an = fdot2(wn2[4*k+3], v3, an);
            }
        }
    }

    float v = h_own * wfc;
#pragma unroll
    for (int off = 32; off >= 1; off >>= 1) v += __shfl_xor(v, off);
    if (lane == 0) out[b] = 0.5f * v + bf0;
}

extern "C" void kernel_launch(void* const* d_in, const int* in_sizes, int n_in,
                              void* d_out, int out_size, void* d_ws, size_t ws_size,
                              hipStream_t stream) {
    const float* x    = (const float*)d_in[0];
    const float* Wih  = (const float*)d_in[1];
    const float* Whh  = (const float*)d_in[2];
    const float* bih  = (const float*)d_in[3];
    const float* bhh  = (const float*)d_in[4];
    const float* Wfc  = (const float*)d_in[5];
    const float* bfc  = (const float*)d_in[6];
    float* out = (float*)d_out;

    const int B = in_sizes[0] / (TS * DD);   // 1024
    const size_t need = (size_t)B * TS * NG * sizeof(_Float16);  // 100.7 MB

    if (ws_size >= need) {
        _Float16* xg = (_Float16*)d_ws;
        xg_gemm<<<dim3(B), dim3(192), 0, stream>>>(x, Wih, bih, xg);
        gru_rec<<<dim3(B), dim3(64), 0, stream>>>(xg, Whh, bhh, Wfc, bfc, out);
    } else {
        gru_fused_fb<<<dim3(B), dim3(64), 0, stream>>>(x, Wih, Whh, bih, bhh, Wfc, bfc, out);
    }
}

// Round 6
// 256.930 us; speedup vs baseline: 1.1497x; 1.1497x over previous
//
#include <hip/hip_runtime.h>

#define TS 512  // timesteps
#define DD 64   // input dim
#define HH 32   // hidden dim
#define NG 96   // 3*HH gates
#define ROWS 256  // (b,t) rows per block in xg_par
#define XST 72    // LDS row stride in halves (144B: 16B-aligned, <=2-way conflict on row reads)

typedef _Float16 half2v __attribute__((ext_vector_type(2)));
typedef _Float16 half4v __attribute__((ext_vector_type(4)));

__device__ __forceinline__ float fdot2(half2v a, half2v b, float c) {
#if __has_builtin(__builtin_amdgcn_fdot2)
    return __builtin_amdgcn_fdot2(a, b, c, false);
#else
    return fmaf((float)a[0], (float)b[0], fmaf((float)a[1], (float)b[1], c));
#endif
}

__device__ __forceinline__ float fast_sigmoid(float a) {
    return __builtin_amdgcn_rcpf(1.0f + __expf(-a));
}

__device__ __forceinline__ half2v h2(unsigned int u) {
    return __builtin_bit_cast(half2v, u);
}

// =====================================================================
// Kernel 1: xg[m][g] = sum_d x[m][d] * Wih[g][d] + bih[g]   (fp16 out)
// m = b*TS + t flattened. Fully parallel: 2048 blocks x 256 threads,
// thread <-> one row. x tile + all of W staged in LDS; W reads are
// wave-broadcast (same address) -> free; 3072 fdot2/thread, no shuffles.
// =====================================================================
__global__ __launch_bounds__(256, 1) void xg_par(
    const float* __restrict__ x,
    const float* __restrict__ Wih,
    const float* __restrict__ bih,
    _Float16* __restrict__ xg)
{
    __shared__ __align__(16) _Float16 xt[ROWS * XST];  // 36864 B
    __shared__ __align__(16) _Float16 wt[NG * DD];     // 12288 B
    __shared__ float bt[NG];

    const int tid = threadIdx.x;
    const size_t rowbase = (size_t)blockIdx.x * ROWS;

    // ---- stage x: 256 rows x 64 f32, coalesced dwordx4 ----
    {
        const float4* xsrc = reinterpret_cast<const float4*>(x + rowbase * DD);
#pragma unroll
        for (int c = 0; c < 16; ++c) {
            int f4 = c * 256 + tid;          // float4 index within tile
            float4 v = xsrc[f4];
            int f   = f4 * 4;                // flat element index
            int row = f >> 6;                // /64
            int k   = f & 63;
            half4v hv{(_Float16)v.x, (_Float16)v.y, (_Float16)v.z, (_Float16)v.w};
            *reinterpret_cast<half4v*>(&xt[row * XST + k]) = hv;
        }
    }
    // ---- stage W (fp16) + bias ----
    {
        const float4* wsrc = reinterpret_cast<const float4*>(Wih);
#pragma unroll
        for (int c = 0; c < 6; ++c) {
            int f4 = c * 256 + tid;          // 1536 float4 total
            float4 v = wsrc[f4];
            int f = f4 * 4;
            half4v hv{(_Float16)v.x, (_Float16)v.y, (_Float16)v.z, (_Float16)v.w};
            *reinterpret_cast<half4v*>(&wt[f]) = hv;
        }
        if (tid < NG) bt[tid] = bih[tid];
    }
    __syncthreads();

    // ---- own row -> 32 half2 regs (8x b128; 16B-aligned: XST*2=144) ----
    half2v xv[32];
#pragma unroll
    for (int r8 = 0; r8 < 8; ++r8) {
        uint4 q = *reinterpret_cast<const uint4*>(&xt[tid * XST + r8 * 8]);
        xv[r8 * 4 + 0] = h2(q.x);
        xv[r8 * 4 + 1] = h2(q.y);
        xv[r8 * 4 + 2] = h2(q.z);
        xv[r8 * 4 + 3] = h2(q.w);
    }

    _Float16* orow = xg + (rowbase + tid) * NG;

    // ---- g-loop: 12 groups of 8 gates; W broadcast from LDS ----
    for (int gg = 0; gg < 12; ++gg) {
        float accs[8];
#pragma unroll
        for (int u = 0; u < 8; ++u) {
            const int g = gg * 8 + u;
            const uint4* wp = reinterpret_cast<const uint4*>(&wt[g * DD]);
            float a0 = bt[g], a1 = 0.f;
#pragma unroll
            for (int k8 = 0; k8 < 8; ++k8) {
                uint4 q = wp[k8];                        // broadcast read
                a0 = fdot2(xv[k8 * 4 + 0], h2(q.x), a0);
                a1 = fdot2(xv[k8 * 4 + 1], h2(q.y), a1);
                a0 = fdot2(xv[k8 * 4 + 2], h2(q.z), a0);
                a1 = fdot2(xv[k8 * 4 + 3], h2(q.w), a1);
            }
            accs[u] = a0 + a1;
        }
        // pack 8 f32 -> 8 fp16 and store 16B
        half2v p0{(_Float16)accs[0], (_Float16)accs[1]};
        half2v p1{(_Float16)accs[2], (_Float16)accs[3]};
        half2v p2{(_Float16)accs[4], (_Float16)accs[5]};
        half2v p3{(_Float16)accs[6], (_Float16)accs[7]};
        uint4 st{__builtin_bit_cast(unsigned int, p0),
                 __builtin_bit_cast(unsigned int, p1),
                 __builtin_bit_cast(unsigned int, p2),
                 __builtin_bit_cast(unsigned int, p3)};
        *reinterpret_cast<uint4*>(&orow[gg * 8]) = st;   // 192B rows: 16B-aligned
    }
}

// =====================================================================
// Kernel 2: recurrence (unchanged from round 5 — passed, ~72us).
// One wave per batch. lane = s*32+h. xg streamed via 3-deep prefetch.
// =====================================================================
__global__ __launch_bounds__(64, 1) void gru_rec(
    const _Float16* __restrict__ xg,
    const float* __restrict__ Whh,
    const float* __restrict__ bhh,
    const float* __restrict__ Wfc,
    const float* __restrict__ bfc,
    float* __restrict__ out)
{
    __shared__ __align__(16) _Float16 hs16[HH];

    const int b    = blockIdx.x;
    const int lane = threadIdx.x;
    const int s    = lane >> 5;
    const int h    = lane & 31;

    half2v ur2[8], uz2[8], un2[8];
    {
        const float4* pr = reinterpret_cast<const float4*>(Whh + (0*HH + h)*HH + s*16);
        const float4* pz = reinterpret_cast<const float4*>(Whh + (1*HH + h)*HH + s*16);
        const float4* pn = reinterpret_cast<const float4*>(Whh + (2*HH + h)*HH + s*16);
#pragma unroll
        for (int k = 0; k < 4; ++k) {
            float4 a = pr[k];
            ur2[2*k]   = half2v{(_Float16)a.x, (_Float16)a.y};
            ur2[2*k+1] = half2v{(_Float16)a.z, (_Float16)a.w};
            float4 c = pz[k];
            uz2[2*k]   = half2v{(_Float16)c.x, (_Float16)c.y};
            uz2[2*k+1] = half2v{(_Float16)c.z, (_Float16)c.w};
            float4 e = pn[k];
            un2[2*k]   = half2v{(_Float16)e.x, (_Float16)e.y};
            un2[2*k+1] = half2v{(_Float16)e.z, (_Float16)e.w};
        }
    }

    const float cr  = bhh[h];
    const float cz  = bhh[HH + h];
    const float cn  = bhh[2*HH + h];
    const float wfc = Wfc[h];
    const float bf0 = bfc[0];

    const _Float16* xb = xg + (size_t)b * TS * NG;

    _Float16 xra = xb[0*NG + h],        xrb = xb[1*NG + h],        xrc = xb[2*NG + h];
    _Float16 xza = xb[0*NG + HH + h],   xzb = xb[1*NG + HH + h],   xzc = xb[2*NG + HH + h];
    _Float16 xna = xb[0*NG + 2*HH + h], xnb = xb[1*NG + 2*HH + h], xnc = xb[2*NG + 2*HH + h];

    float h_own = 0.f;
    half2v hv2[8];
#pragma unroll
    for (int k = 0; k < 8; ++k) hv2[k] = half2v{(_Float16)0.0f, (_Float16)0.0f};

    for (int t = 0; t < TS; ++t) {
        float xrv = (float)xra;
        float xzv = (float)xza;
        float xnv = (float)xna;
        xra = xrb; xrb = xrc;
        xza = xzb; xzb = xzc;
        xna = xnb; xnb = xnc;
        int tf = t + 3; if (tf > TS - 1) tf = TS - 1;
        xrc = xb[tf*NG + h];
        xzc = xb[tf*NG + HH + h];
        xnc = xb[tf*NG + 2*HH + h];

        float gr0 = 0.f, gr1 = 0.f, gz0 = 0.f, gz1 = 0.f, gn0 = 0.f, gn1 = 0.f;
#pragma unroll
        for (int k = 0; k < 4; ++k) {
            gr0 = fdot2(ur2[2*k  ], hv2[2*k  ], gr0);
            gr1 = fdot2(ur2[2*k+1], hv2[2*k+1], gr1);
            gz0 = fdot2(uz2[2*k  ], hv2[2*k  ], gz0);
            gz1 = fdot2(uz2[2*k+1], hv2[2*k+1], gz1);
            gn0 = fdot2(un2[2*k  ], hv2[2*k  ], gn0);
            gn1 = fdot2(un2[2*k+1], hv2[2*k+1], gn1);
        }
        float gr = gr0 + gr1;
        float gz = gz0 + gz1;
        float gn = gn0 + gn1;
        gr += __shfl_xor(gr, 32);
        gz += __shfl_xor(gz, 32);
        gn += __shfl_xor(gn, 32);

        float r = fast_sigmoid(xrv + cr + gr);
        float z = fast_sigmoid(xzv + cz + gz);
        float npre = xnv + r * (gn + cn);
        npre = fminf(fmaxf(npre, -30.f), 30.f);
        float e2 = __expf(-2.f * npre);
        float n = (1.f - e2) * __builtin_amdgcn_rcpf(1.f + e2);
        h_own = n + z * (h_own - n);

        hs16[h] = (_Float16)h_own;
        __builtin_amdgcn_wave_barrier();
        {
            const uint4* hp = reinterpret_cast<const uint4*>(&hs16[s * 16]);
            uint4 q0 = hp[0];
            uint4 q1 = hp[1];
            hv2[0] = h2(q0.x);
            hv2[1] = h2(q0.y);
            hv2[2] = h2(q0.z);
            hv2[3] = h2(q0.w);
            hv2[4] = h2(q1.x);
            hv2[5] = h2(q1.y);
            hv2[6] = h2(q1.z);
            hv2[7] = h2(q1.w);
        }
    }

    float v = h_own * wfc;
#pragma unroll
    for (int off = 32; off >= 1; off >>= 1) v += __shfl_xor(v, off);
    if (lane == 0) out[b] = 0.5f * v + bf0;
}

// =====================================================================
// Fallback (round-2 kernel, known-passing) if ws is too small.
// =====================================================================
__global__ __launch_bounds__(64, 1) void gru_fused_fb(
    const float* __restrict__ x,
    const float* __restrict__ Wih,
    const float* __restrict__ Whh,
    const float* __restrict__ bih,
    const float* __restrict__ bhh,
    const float* __restrict__ Wfc,
    const float* __restrict__ bfc,
    float* __restrict__ out)
{
    __shared__ __align__(16) _Float16 xs16[4][DD];
    __shared__ __align__(16) _Float16 hs16[HH];

    const int b    = blockIdx.x;
    const int lane = threadIdx.x;
    const int s    = lane >> 5;
    const int h    = lane & 31;

    half2v wr2[16], wz2[16], wn2[16];
    {
        const float4* pr = reinterpret_cast<const float4*>(Wih + (0*HH + h)*DD + s*32);
        const float4* pz = reinterpret_cast<const float4*>(Wih + (1*HH + h)*DD + s*32);
        const float4* pn = reinterpret_cast<const float4*>(Wih + (2*HH + h)*DD + s*32);
#pragma unroll
        for (int k = 0; k < 8; ++k) {
            float4 a = pr[k];
            wr2[2*k]   = half2v{(_Float16)a.x, (_Float16)a.y};
            wr2[2*k+1] = half2v{(_Float16)a.z, (_Float16)a.w};
            float4 c = pz[k];
            wz2[2*k]   = half2v{(_Float16)c.x, (_Float16)c.y};
            wz2[2*k+1] = half2v{(_Float16)c.z, (_Float16)c.w};
            float4 e = pn[k];
            wn2[2*k]   = half2v{(_Float16)e.x, (_Float16)e.y};
            wn2[2*k+1] = half2v{(_Float16)e.z, (_Float16)e.w};
        }
    }
    half2v ur2[8], uz2[8], un2[8];
    {
        const float4* pr = reinterpret_cast<const float4*>(Whh + (0*HH + h)*HH + s*16);
        const float4* pz = reinterpret_cast<const float4*>(Whh + (1*HH + h)*HH + s*16);
        const float4* pn = reinterpret_cast<const float4*>(Whh + (2*HH + h)*HH + s*16);
#pragma unroll
        for (int k = 0; k < 4; ++k) {
            float4 a = pr[k];
            ur2[2*k]   = half2v{(_Float16)a.x, (_Float16)a.y};
            ur2[2*k+1] = half2v{(_Float16)a.z, (_Float16)a.w};
            float4 c = pz[k];
            uz2[2*k]   = half2v{(_Float16)c.x, (_Float16)c.y};
            uz2[2*k+1] = half2v{(_Float16)c.z, (_Float16)c.w};
            float4 e = pn[k];
            un2[2*k]   = half2v{(_Float16)e.x, (_Float16)e.y};
            un2[2*k+1] = half2v{(_Float16)e.z, (_Float16)e.w};
        }
    }

    const float br  = bih[h]        + bhh[h];
    const float bz  = bih[HH + h]   + bhh[HH + h];
    const float bxn = bih[2*HH + h];
    const float bhn = bhh[2*HH + h];
    const float wfc = Wfc[h];
    const float bf0 = bfc[0];

    const float* xrow = x + (size_t)b * TS * DD;

    float p0 = xrow[0*DD + lane];
    float p1 = xrow[1*DD + lane];
    float p2 = xrow[2*DD + lane];
    float ra = xrow[3*DD + lane];
    float rb = xrow[4*DD + lane];
    float rc = xrow[5*DD + lane];
    xs16[0][lane] = (_Float16)p0;
    xs16[1][lane] = (_Float16)p1;
    xs16[2][lane] = (_Float16)p2;
    __builtin_amdgcn_wave_barrier();

    float h_own = 0.0f;
    half2v hv2[8];
#pragma unroll
    for (int k = 0; k < 8; ++k) hv2[k] = half2v{(_Float16)0.0f, (_Float16)0.0f};

    float ar, az, an;
    {
        const uint4* xp = reinterpret_cast<const uint4*>(&xs16[0][s * 32]);
        ar = 0.f; az = 0.f; an = 0.f;
#pragma unroll
        for (int k = 0; k < 4; ++k) {
            uint4 q = xp[k];
            half2v v0 = h2(q.x), v1 = h2(q.y), v2 = h2(q.z), v3 = h2(q.w);
            ar = fdot2(wr2[4*k  ], v0, ar);  az = fdot2(wz2[4*k  ], v0, az);  an = fdot2(wn2[4*k  ], v0, an);
            ar = fdot2(wr2[4*k+1], v1, ar);  az = fdot2(wz2[4*k+1], v1, az);  an = fdot2(wn2[4*k+1], v1, an);
            ar = fdot2(wr2[4*k+2], v2, ar);  az = fdot2(wz2[4*k+2], v2, az);  an = fdot2(wn2[4*k+2], v2, an);
            ar = fdot2(wr2[4*k+3], v3, ar);  az = fdot2(wz2[4*k+3], v3, az);  an = fdot2(wn2[4*k+3], v3, an);
        }
    }

    for (int t = 0; t < TS; ++t) {
        xs16[(t + 3) & 3][lane] = (_Float16)ra;
        ra = rb; rb = rc;
        int tf = t + 6; if (tf > TS - 1) tf = TS - 1;
        rc = xrow[tf * DD + lane];

        float gr = 0.f, gz = 0.f, gn = 0.f;
#pragma unroll
        for (int k = 0; k < 8; ++k) {
            gr = fdot2(ur2[k], hv2[k], gr);
            gz = fdot2(uz2[k], hv2[k], gz);
            gn = fdot2(un2[k], hv2[k], gn);
        }

        float tr = ar + gr;  tr += __shfl_xor(tr, 32);
        float tz = az + gz;  tz += __shfl_xor(tz, 32);
        float txn = an + __shfl_xor(an, 32);
        float tgn = gn + __shfl_xor(gn, 32);

        float r = fast_sigmoid(tr + br);
        float z = fast_sigmoid(tz + bz);
        float npre = txn + bxn + r * (tgn + bhn);
        npre = fminf(fmaxf(npre, -30.f), 30.f);
        float e2 = __expf(-2.f * npre);
        float n = (1.f - e2) * __builtin_amdgcn_rcpf(1.f + e2);
        h_own = n + z * (h_own - n);

        hs16[h] = (_Float16)h_own;
        __builtin_amdgcn_wave_barrier();
        {
            const uint4* hp = reinterpret_cast<const uint4*>(&hs16[s * 16]);
            uint4 q0 = hp[0];
            uint4 q1 = hp[1];
            hv2[0] = h2(q0.x);
            hv2[1] = h2(q0.y);
            hv2[2] = h2(q0.z);
            hv2[3] = h2(q0.w);
            hv2[4] = h2(q1.x);
            hv2[5] = h2(q1.y);
            hv2[6] = h2(q1.z);
            hv2[7] = h2(q1.w);
        }

        if (t + 1 < TS) {
            const uint4* xp = reinterpret_cast<const uint4*>(&xs16[(t + 1) & 3][s * 32]);
            ar = 0.f; az = 0.f; an = 0.f;
#pragma unroll
            for (int k = 0; k < 4; ++k) {
                uint4 q = xp[k];
                half2v v0 = h2(q.x), v1 = h2(q.y), v2 = h2(q.z), v3 = h2(q.w);
                ar = fdot2(wr2[4*k  ], v0, ar);  az = fdot2(wz2[4*k  ], v0, az);  an = fdot2(wn2[4*k  ], v0, an);
                ar = fdot2(wr2[4*k+1], v1, ar);  az = fdot2(wz2[4*k+1], v1, az);  an = fdot2(wn2[4*k+1], v1, an);
                ar = fdot2(wr2[4*k+2], v2, ar);  az = fdot2(wz2[4*k+2], v2, az);  an = fdot2(wn2[4*k+2], v2, an);
                ar = fdot2(wr2[4*k+3], v3, ar);  az = fdot2(wz2[4*k+3], v3, az);  an = fdot2(wn2[4*k+3], v3, an);
            }
        }
    }

    float v = h_own * wfc;
#pragma unroll
    for (int off = 32; off >= 1; off >>= 1) v += __shfl_xor(v, off);
    if (lane == 0) out[b] = 0.5f * v + bf0;
}

extern "C" void kernel_launch(void* const* d_in, const int* in_sizes, int n_in,
                              void* d_out, int out_size, void* d_ws, size_t ws_size,
                              hipStream_t stream) {
    const float* x    = (const float*)d_in[0];
    const float* Wih  = (const float*)d_in[1];
    const float* Whh  = (const float*)d_in[2];
    const float* bih  = (const float*)d_in[3];
    const float* bhh  = (const float*)d_in[4];
    const float* Wfc  = (const float*)d_in[5];
    const float* bfc  = (const float*)d_in[6];
    float* out = (float*)d_out;

    const int B = in_sizes[0] / (TS * DD);   // 1024
    const int M = B * TS;                    // 524288 rows
    const size_t need = (size_t)M * NG * sizeof(_Float16);  // 100.7 MB

    if (ws_size >= need && (M % ROWS) == 0) {
        _Float16* xg = (_Float16*)d_ws;
        xg_par<<<dim3(M / ROWS), dim3(256), 0, stream>>>(x, Wih, bih, xg);
        gru_rec<<<dim3(B), dim3(64), 0, stream>>>(xg, Whh, bhh, Wfc, bfc, out);
    } else {
        gru_fused_fb<<<dim3(B), dim3(64), 0, stream>>>(x, Wih, Whh, bih, bhh, Wfc, bfc, out);
    }
}

// Round 7
// 248.450 us; speedup vs baseline: 1.1890x; 1.0341x over previous
//
#include <hip/hip_runtime.h>

#define TS 512  // timesteps
#define DD 64   // input dim
#define HH 32   // hidden dim
#define NG 96   // 3*HH gates
#define ROWS 256  // (b,t) rows per block in xg_par
#define XST 72    // LDS row stride in halves (144B = 9*16B: aligned, spreads banks)

typedef _Float16 half2v __attribute__((ext_vector_type(2)));
typedef _Float16 half4v __attribute__((ext_vector_type(4)));

__device__ __forceinline__ float fdot2(half2v a, half2v b, float c) {
#if __has_builtin(__builtin_amdgcn_fdot2)
    return __builtin_amdgcn_fdot2(a, b, c, false);
#else
    return fmaf((float)a[0], (float)b[0], fmaf((float)a[1], (float)b[1], c));
#endif
}

__device__ __forceinline__ float fast_sigmoid(float a) {
    return __builtin_amdgcn_rcpf(1.0f + __expf(-a));
}

__device__ __forceinline__ half2v h2(unsigned int u) {
    return __builtin_bit_cast(half2v, u);
}

// =====================================================================
// Kernel 1: xg[m][g] = sum_d x[m][d] * Wih[g][d] + bih[g]   (fp16 out)
// 128 threads/block, 256 rows/block -> 2 rows per thread. W broadcast
// reads from LDS amortize over 2 rows (halves DS-pipe pressure vs r6).
// waves_per_eu(1,2): 256-VGPR budget so the 64 xv regs stay resident.
// =====================================================================
__global__ __launch_bounds__(128)
__attribute__((amdgpu_waves_per_eu(1, 2)))
void xg_par(
    const float* __restrict__ x,
    const float* __restrict__ Wih,
    const float* __restrict__ bih,
    _Float16* __restrict__ xg)
{
    __shared__ __align__(16) _Float16 xt[ROWS * XST];  // 36864 B
    __shared__ __align__(16) _Float16 wt[NG * DD];     // 12288 B
    __shared__ float bt[NG];

    const int tid = threadIdx.x;
    const size_t rowbase = (size_t)blockIdx.x * ROWS;

    // ---- stage x: 256 rows x 64 f32, coalesced dwordx4 ----
    {
        const float4* xsrc = reinterpret_cast<const float4*>(x + rowbase * DD);
#pragma unroll
        for (int c = 0; c < 32; ++c) {
            int f4 = c * 128 + tid;          // float4 index within tile (0..4095)
            float4 v = xsrc[f4];
            int f   = f4 * 4;                // flat element index
            int row = f >> 6;                // /64
            int k   = f & 63;
            half4v hv{(_Float16)v.x, (_Float16)v.y, (_Float16)v.z, (_Float16)v.w};
            *reinterpret_cast<half4v*>(&xt[row * XST + k]) = hv;
        }
    }
    // ---- stage W (fp16) + bias ----
    {
        const float4* wsrc = reinterpret_cast<const float4*>(Wih);
#pragma unroll
        for (int c = 0; c < 12; ++c) {
            int f4 = c * 128 + tid;          // 1536 float4 total
            float4 v = wsrc[f4];
            int f = f4 * 4;
            half4v hv{(_Float16)v.x, (_Float16)v.y, (_Float16)v.z, (_Float16)v.w};
            *reinterpret_cast<half4v*>(&wt[f]) = hv;
        }
        if (tid < NG) bt[tid] = bih[tid];
    }
    __syncthreads();

    // ---- own 2 rows -> 64 half2 regs ----
    half2v xv0[32], xv1[32];
#pragma unroll
    for (int r8 = 0; r8 < 8; ++r8) {
        uint4 q = *reinterpret_cast<const uint4*>(&xt[tid * XST + r8 * 8]);
        xv0[r8*4+0] = h2(q.x); xv0[r8*4+1] = h2(q.y);
        xv0[r8*4+2] = h2(q.z); xv0[r8*4+3] = h2(q.w);
        uint4 p = *reinterpret_cast<const uint4*>(&xt[(tid + 128) * XST + r8 * 8]);
        xv1[r8*4+0] = h2(p.x); xv1[r8*4+1] = h2(p.y);
        xv1[r8*4+2] = h2(p.z); xv1[r8*4+3] = h2(p.w);
    }

    _Float16* orow0 = xg + (rowbase + tid) * NG;
    _Float16* orow1 = xg + (rowbase + tid + 128) * NG;

    // ---- g-loop: 12 groups of 8 gates; W broadcast shared by both rows ----
    for (int gg = 0; gg < 12; ++gg) {
        float acc0[8], acc1[8];
#pragma unroll
        for (int u = 0; u < 8; ++u) {
            const int g = gg * 8 + u;
            const uint4* wp = reinterpret_cast<const uint4*>(&wt[g * DD]);
            float a0 = bt[g], a1 = 0.f;     // row 0 chains
            float b0 = bt[g], b1 = 0.f;     // row 1 chains
#pragma unroll
            for (int k8 = 0; k8 < 8; ++k8) {
                uint4 q = wp[k8];                        // broadcast read
                half2v w0 = h2(q.x), w1 = h2(q.y), w2 = h2(q.z), w3 = h2(q.w);
                a0 = fdot2(xv0[k8*4+0], w0, a0);
                a1 = fdot2(xv0[k8*4+1], w1, a1);
                b0 = fdot2(xv1[k8*4+0], w0, b0);
                b1 = fdot2(xv1[k8*4+1], w1, b1);
                a0 = fdot2(xv0[k8*4+2], w2, a0);
                a1 = fdot2(xv0[k8*4+3], w3, a1);
                b0 = fdot2(xv1[k8*4+2], w2, b0);
                b1 = fdot2(xv1[k8*4+3], w3, b1);
            }
            acc0[u] = a0 + a1;
            acc1[u] = b0 + b1;
        }
        // pack 8 f32 -> 8 fp16 and store 16B per row
        {
            half2v p0{(_Float16)acc0[0], (_Float16)acc0[1]};
            half2v p1{(_Float16)acc0[2], (_Float16)acc0[3]};
            half2v p2{(_Float16)acc0[4], (_Float16)acc0[5]};
            half2v p3{(_Float16)acc0[6], (_Float16)acc0[7]};
            uint4 st{__builtin_bit_cast(unsigned int, p0),
                     __builtin_bit_cast(unsigned int, p1),
                     __builtin_bit_cast(unsigned int, p2),
                     __builtin_bit_cast(unsigned int, p3)};
            *reinterpret_cast<uint4*>(&orow0[gg * 8]) = st;
        }
        {
            half2v p0{(_Float16)acc1[0], (_Float16)acc1[1]};
            half2v p1{(_Float16)acc1[2], (_Float16)acc1[3]};
            half2v p2{(_Float16)acc1[4], (_Float16)acc1[5]};
            half2v p3{(_Float16)acc1[6], (_Float16)acc1[7]};
            uint4 st{__builtin_bit_cast(unsigned int, p0),
                     __builtin_bit_cast(unsigned int, p1),
                     __builtin_bit_cast(unsigned int, p2),
                     __builtin_bit_cast(unsigned int, p3)};
            *reinterpret_cast<uint4*>(&orow1[gg * 8]) = st;
        }
    }
}

// =====================================================================
// Kernel 2: recurrence (source identical to round 5/6).
// waves_per_eu(1,1): occupancy is grid-limited to 1 wave/EU anyway, so
// give the allocator the full 512-VGPR budget -> weights stay resident.
// =====================================================================
__global__ __launch_bounds__(64)
__attribute__((amdgpu_waves_per_eu(1, 1)))
void gru_rec(
    const _Float16* __restrict__ xg,
    const float* __restrict__ Whh,
    const float* __restrict__ bhh,
    const float* __restrict__ Wfc,
    const float* __restrict__ bfc,
    float* __restrict__ out)
{
    __shared__ __align__(16) _Float16 hs16[HH];

    const int b    = blockIdx.x;
    const int lane = threadIdx.x;
    const int s    = lane >> 5;
    const int h    = lane & 31;

    half2v ur2[8], uz2[8], un2[8];
    {
        const float4* pr = reinterpret_cast<const float4*>(Whh + (0*HH + h)*HH + s*16);
        const float4* pz = reinterpret_cast<const float4*>(Whh + (1*HH + h)*HH + s*16);
        const float4* pn = reinterpret_cast<const float4*>(Whh + (2*HH + h)*HH + s*16);
#pragma unroll
        for (int k = 0; k < 4; ++k) {
            float4 a = pr[k];
            ur2[2*k]   = half2v{(_Float16)a.x, (_Float16)a.y};
            ur2[2*k+1] = half2v{(_Float16)a.z, (_Float16)a.w};
            float4 c = pz[k];
            uz2[2*k]   = half2v{(_Float16)c.x, (_Float16)c.y};
            uz2[2*k+1] = half2v{(_Float16)c.z, (_Float16)c.w};
            float4 e = pn[k];
            un2[2*k]   = half2v{(_Float16)e.x, (_Float16)e.y};
            un2[2*k+1] = half2v{(_Float16)e.z, (_Float16)e.w};
        }
    }

    const float cr  = bhh[h];
    const float cz  = bhh[HH + h];
    const float cn  = bhh[2*HH + h];
    const float wfc = Wfc[h];
    const float bf0 = bfc[0];

    const _Float16* xb = xg + (size_t)b * TS * NG;

    _Float16 xra = xb[0*NG + h],        xrb = xb[1*NG + h],        xrc = xb[2*NG + h];
    _Float16 xza = xb[0*NG + HH + h],   xzb = xb[1*NG + HH + h],   xzc = xb[2*NG + HH + h];
    _Float16 xna = xb[0*NG + 2*HH + h], xnb = xb[1*NG + 2*HH + h], xnc = xb[2*NG + 2*HH + h];

    float h_own = 0.f;
    half2v hv2[8];
#pragma unroll
    for (int k = 0; k < 8; ++k) hv2[k] = half2v{(_Float16)0.0f, (_Float16)0.0f};

    for (int t = 0; t < TS; ++t) {
        float xrv = (float)xra;
        float xzv = (float)xza;
        float xnv = (float)xna;
        xra = xrb; xrb = xrc;
        xza = xzb; xzb = xzc;
        xna = xnb; xnb = xnc;
        int tf = t + 3; if (tf > TS - 1) tf = TS - 1;
        xrc = xb[tf*NG + h];
        xzc = xb[tf*NG + HH + h];
        xnc = xb[tf*NG + 2*HH + h];

        float gr0 = 0.f, gr1 = 0.f, gz0 = 0.f, gz1 = 0.f, gn0 = 0.f, gn1 = 0.f;
#pragma unroll
        for (int k = 0; k < 4; ++k) {
            gr0 = fdot2(ur2[2*k  ], hv2[2*k  ], gr0);
            gr1 = fdot2(ur2[2*k+1], hv2[2*k+1], gr1);
            gz0 = fdot2(uz2[2*k  ], hv2[2*k  ], gz0);
            gz1 = fdot2(uz2[2*k+1], hv2[2*k+1], gz1);
            gn0 = fdot2(un2[2*k  ], hv2[2*k  ], gn0);
            gn1 = fdot2(un2[2*k+1], hv2[2*k+1], gn1);
        }
        float gr = gr0 + gr1;
        float gz = gz0 + gz1;
        float gn = gn0 + gn1;
        gr += __shfl_xor(gr, 32);
        gz += __shfl_xor(gz, 32);
        gn += __shfl_xor(gn, 32);

        float r = fast_sigmoid(xrv + cr + gr);
        float z = fast_sigmoid(xzv + cz + gz);
        float npre = xnv + r * (gn + cn);
        npre = fminf(fmaxf(npre, -30.f), 30.f);
        float e2 = __expf(-2.f * npre);
        float n = (1.f - e2) * __builtin_amdgcn_rcpf(1.f + e2);
        h_own = n + z * (h_own - n);

        hs16[h] = (_Float16)h_own;
        __builtin_amdgcn_wave_barrier();
        {
            const uint4* hp = reinterpret_cast<const uint4*>(&hs16[s * 16]);
            uint4 q0 = hp[0];
            uint4 q1 = hp[1];
            hv2[0] = h2(q0.x);
            hv2[1] = h2(q0.y);
            hv2[2] = h2(q0.z);
            hv2[3] = h2(q0.w);
            hv2[4] = h2(q1.x);
            hv2[5] = h2(q1.y);
            hv2[6] = h2(q1.z);
            hv2[7] = h2(q1.w);
        }
    }

    float v = h_own * wfc;
#pragma unroll
    for (int off = 32; off >= 1; off >>= 1) v += __shfl_xor(v, off);
    if (lane == 0) out[b] = 0.5f * v + bf0;
}

// =====================================================================
// Fallback (round-2 kernel, known-passing) if ws is too small.
// =====================================================================
__global__ __launch_bounds__(64, 1) void gru_fused_fb(
    const float* __restrict__ x,
    const float* __restrict__ Wih,
    const float* __restrict__ Whh,
    const float* __restrict__ bih,
    const float* __restrict__ bhh,
    const float* __restrict__ Wfc,
    const float* __restrict__ bfc,
    float* __restrict__ out)
{
    __shared__ __align__(16) _Float16 xs16[4][DD];
    __shared__ __align__(16) _Float16 hs16[HH];

    const int b    = blockIdx.x;
    const int lane = threadIdx.x;
    const int s    = lane >> 5;
    const int h    = lane & 31;

    half2v wr2[16], wz2[16], wn2[16];
    {
        const float4* pr = reinterpret_cast<const float4*>(Wih + (0*HH + h)*DD + s*32);
        const float4* pz = reinterpret_cast<const float4*>(Wih + (1*HH + h)*DD + s*32);
        const float4* pn = reinterpret_cast<const float4*>(Wih + (2*HH + h)*DD + s*32);
#pragma unroll
        for (int k = 0; k < 8; ++k) {
            float4 a = pr[k];
            wr2[2*k]   = half2v{(_Float16)a.x, (_Float16)a.y};
            wr2[2*k+1] = half2v{(_Float16)a.z, (_Float16)a.w};
            float4 c = pz[k];
            wz2[2*k]   = half2v{(_Float16)c.x, (_Float16)c.y};
            wz2[2*k+1] = half2v{(_Float16)c.z, (_Float16)c.w};
            float4 e = pn[k];
            wn2[2*k]   = half2v{(_Float16)e.x, (_Float16)e.y};
            wn2[2*k+1] = half2v{(_Float16)e.z, (_Float16)e.w};
        }
    }
    half2v ur2[8], uz2[8], un2[8];
    {
        const float4* pr = reinterpret_cast<const float4*>(Whh + (0*HH + h)*HH + s*16);
        const float4* pz = reinterpret_cast<const float4*>(Whh + (1*HH + h)*HH + s*16);
        const float4* pn = reinterpret_cast<const float4*>(Whh + (2*HH + h)*HH + s*16);
#pragma unroll
        for (int k = 0; k < 4; ++k) {
            float4 a = pr[k];
            ur2[2*k]   = half2v{(_Float16)a.x, (_Float16)a.y};
            ur2[2*k+1] = half2v{(_Float16)a.z, (_Float16)a.w};
            float4 c = pz[k];
            uz2[2*k]   = half2v{(_Float16)c.x, (_Float16)c.y};
            uz2[2*k+1] = half2v{(_Float16)c.z, (_Float16)c.w};
            float4 e = pn[k];
            un2[2*k]   = half2v{(_Float16)e.x, (_Float16)e.y};
            un2[2*k+1] = half2v{(_Float16)e.z, (_Float16)e.w};
        }
    }

    const float br  = bih[h]        + bhh[h];
    const float bz  = bih[HH + h]   + bhh[HH + h];
    const float bxn = bih[2*HH + h];
    const float bhn = bhh[2*HH + h];
    const float wfc = Wfc[h];
    const float bf0 = bfc[0];

    const float* xrow = x + (size_t)b * TS * DD;

    float p0 = xrow[0*DD + lane];
    float p1 = xrow[1*DD + lane];
    float p2 = xrow[2*DD + lane];
    float ra = xrow[3*DD + lane];
    float rb = xrow[4*DD + lane];
    float rc = xrow[5*DD + lane];
    xs16[0][lane] = (_Float16)p0;
    xs16[1][lane] = (_Float16)p1;
    xs16[2][lane] = (_Float16)p2;
    __builtin_amdgcn_wave_barrier();

    float h_own = 0.0f;
    half2v hv2[8];
#pragma unroll
    for (int k = 0; k < 8; ++k) hv2[k] = half2v{(_Float16)0.0f, (_Float16)0.0f};

    float ar, az, an;
    {
        const uint4* xp = reinterpret_cast<const uint4*>(&xs16[0][s * 32]);
        ar = 0.f; az = 0.f; an = 0.f;
#pragma unroll
        for (int k = 0; k < 4; ++k) {
            uint4 q = xp[k];
            half2v v0 = h2(q.x), v1 = h2(q.y), v2 = h2(q.z), v3 = h2(q.w);
            ar = fdot2(wr2[4*k  ], v0, ar);  az = fdot2(wz2[4*k  ], v0, az);  an = fdot2(wn2[4*k  ], v0, an);
            ar = fdot2(wr2[4*k+1], v1, ar);  az = fdot2(wz2[4*k+1], v1, az);  an = fdot2(wn2[4*k+1], v1, an);
            ar = fdot2(wr2[4*k+2], v2, ar);  az = fdot2(wz2[4*k+2], v2, az);  an = fdot2(wn2[4*k+2], v2, an);
            ar = fdot2(wr2[4*k+3], v3, ar);  az = fdot2(wz2[4*k+3], v3, az);  an = fdot2(wn2[4*k+3], v3, an);
        }
    }

    for (int t = 0; t < TS; ++t) {
        xs16[(t + 3) & 3][lane] = (_Float16)ra;
        ra = rb; rb = rc;
        int tf = t + 6; if (tf > TS - 1) tf = TS - 1;
        rc = xrow[tf * DD + lane];

        float gr = 0.f, gz = 0.f, gn = 0.f;
#pragma unroll
        for (int k = 0; k < 8; ++k) {
            gr = fdot2(ur2[k], hv2[k], gr);
            gz = fdot2(uz2[k], hv2[k], gz);
            gn = fdot2(un2[k], hv2[k], gn);
        }

        float tr = ar + gr;  tr += __shfl_xor(tr, 32);
        float tz = az + gz;  tz += __shfl_xor(tz, 32);
        float txn = an + __shfl_xor(an, 32);
        float tgn = gn + __shfl_xor(gn, 32);

        float r = fast_sigmoid(tr + br);
        float z = fast_sigmoid(tz + bz);
        float npre = txn + bxn + r * (tgn + bhn);
        npre = fminf(fmaxf(npre, -30.f), 30.f);
        float e2 = __expf(-2.f * npre);
        float n = (1.f - e2) * __builtin_amdgcn_rcpf(1.f + e2);
        h_own = n + z * (h_own - n);

        hs16[h] = (_Float16)h_own;
        __builtin_amdgcn_wave_barrier();
        {
            const uint4* hp = reinterpret_cast<const uint4*>(&hs16[s * 16]);
            uint4 q0 = hp[0];
            uint4 q1 = hp[1];
            hv2[0] = h2(q0.x);
            hv2[1] = h2(q0.y);
            hv2[2] = h2(q0.z);
            hv2[3] = h2(q0.w);
            hv2[4] = h2(q1.x);
            hv2[5] = h2(q1.y);
            hv2[6] = h2(q1.z);
            hv2[7] = h2(q1.w);
        }

        if (t + 1 < TS) {
            const uint4* xp = reinterpret_cast<const uint4*>(&xs16[(t + 1) & 3][s * 32]);
            ar = 0.f; az = 0.f; an = 0.f;
#pragma unroll
            for (int k = 0; k < 4; ++k) {
                uint4 q = xp[k];
                half2v v0 = h2(q.x), v1 = h2(q.y), v2 = h2(q.z), v3 = h2(q.w);
                ar = fdot2(wr2[4*k  ], v0, ar);  az = fdot2(wz2[4*k  ], v0, az);  an = fdot2(wn2[4*k  ], v0, an);
                ar = fdot2(wr2[4*k+1], v1, ar);  az = fdot2(wz2[4*k+1], v1, az);  an = fdot2(wn2[4*k+1], v1, an);
                ar = fdot2(wr2[4*k+2], v2, ar);  az = fdot2(wz2[4*k+2], v2, az);  an = fdot2(wn2[4*k+2], v2, an);
                ar = fdot2(wr2[4*k+3], v3, ar);  az = fdot2(wz2[4*k+3], v3, az);  an = fdot2(wn2[4*k+3], v3, an);
            }
        }
    }

    float v = h_own * wfc;
#pragma unroll
    for (int off = 32; off >= 1; off >>= 1) v += __shfl_xor(v, off);
    if (lane == 0) out[b] = 0.5f * v + bf0;
}

extern "C" void kernel_launch(void* const* d_in, const int* in_sizes, int n_in,
                              void* d_out, int out_size, void* d_ws, size_t ws_size,
                              hipStream_t stream) {
    const float* x    = (const float*)d_in[0];
    const float* Wih  = (const float*)d_in[1];
    const float* Whh  = (const float*)d_in[2];
    const float* bih  = (const float*)d_in[3];
    const float* bhh  = (const float*)d_in[4];
    const float* Wfc  = (const float*)d_in[5];
    const float* bfc  = (const float*)d_in[6];
    float* out = (float*)d_out;

    const int B = in_sizes[0] / (TS * DD);   // 1024
    const int M = B * TS;                    // 524288 rows
    const size_t need = (size_t)M * NG * sizeof(_Float16);  // 100.7 MB

    if (ws_size >= need && (M % ROWS) == 0) {
        _Float16* xg = (_Float16*)d_ws;
        xg_par<<<dim3(M / ROWS), dim3(128), 0, stream>>>(x, Wih, bih, xg);
        gru_rec<<<dim3(B), dim3(64), 0, stream>>>(xg, Whh, bhh, Wfc, bfc, out);
    } else {
        gru_fused_fb<<<dim3(B), dim3(64), 0, stream>>>(x, Wih, Whh, bih, bhh, Wfc, bfc, out);
    }
}

// Round 8
// 240.948 us; speedup vs baseline: 1.2260x; 1.0311x over previous
//
#include <hip/hip_runtime.h>

#define TS 512  // timesteps
#define DD 64   // input dim
#define HH 32   // hidden dim
#define NG 96   // 3*HH gates
#define ROWS 256  // (b,t) rows per block in xg_par
#define XST 72    // LDS row stride in halves

typedef _Float16 half2v __attribute__((ext_vector_type(2)));
typedef _Float16 half4v __attribute__((ext_vector_type(4)));

__device__ __forceinline__ float fdot2(half2v a, half2v b, float c) {
#if __has_builtin(__builtin_amdgcn_fdot2)
    return __builtin_amdgcn_fdot2(a, b, c, false);
#else
    return fmaf((float)a[0], (float)b[0], fmaf((float)a[1], (float)b[1], c));
#endif
}

__device__ __forceinline__ float fast_sigmoid(float a) {
    return __builtin_amdgcn_rcpf(1.0f + __expf(-a));
}

__device__ __forceinline__ half2v h2(unsigned int u) {
    return __builtin_bit_cast(half2v, u);
}

// =====================================================================
// Kernel 1: xg[m][g] = sum_d x[m][d] * Wih[g][d] + bih[g]   (fp16 out)
// EXACT round-6 version (measured ~74us): 256 threads, 1 row/thread,
// W broadcast from LDS, 3 waves/SIMD occupancy.
// =====================================================================
__global__ __launch_bounds__(256, 1) void xg_par(
    const float* __restrict__ x,
    const float* __restrict__ Wih,
    const float* __restrict__ bih,
    _Float16* __restrict__ xg)
{
    __shared__ __align__(16) _Float16 xt[ROWS * XST];  // 36864 B
    __shared__ __align__(16) _Float16 wt[NG * DD];     // 12288 B
    __shared__ float bt[NG];

    const int tid = threadIdx.x;
    const size_t rowbase = (size_t)blockIdx.x * ROWS;

    // ---- stage x: 256 rows x 64 f32, coalesced dwordx4 ----
    {
        const float4* xsrc = reinterpret_cast<const float4*>(x + rowbase * DD);
#pragma unroll
        for (int c = 0; c < 16; ++c) {
            int f4 = c * 256 + tid;          // float4 index within tile
            float4 v = xsrc[f4];
            int f   = f4 * 4;                // flat element index
            int row = f >> 6;                // /64
            int k   = f & 63;
            half4v hv{(_Float16)v.x, (_Float16)v.y, (_Float16)v.z, (_Float16)v.w};
            *reinterpret_cast<half4v*>(&xt[row * XST + k]) = hv;
        }
    }
    // ---- stage W (fp16) + bias ----
    {
        const float4* wsrc = reinterpret_cast<const float4*>(Wih);
#pragma unroll
        for (int c = 0; c < 6; ++c) {
            int f4 = c * 256 + tid;          // 1536 float4 total
            float4 v = wsrc[f4];
            int f = f4 * 4;
            half4v hv{(_Float16)v.x, (_Float16)v.y, (_Float16)v.z, (_Float16)v.w};
            *reinterpret_cast<half4v*>(&wt[f]) = hv;
        }
        if (tid < NG) bt[tid] = bih[tid];
    }
    __syncthreads();

    // ---- own row -> 32 half2 regs ----
    half2v xv[32];
#pragma unroll
    for (int r8 = 0; r8 < 8; ++r8) {
        uint4 q = *reinterpret_cast<const uint4*>(&xt[tid * XST + r8 * 8]);
        xv[r8 * 4 + 0] = h2(q.x);
        xv[r8 * 4 + 1] = h2(q.y);
        xv[r8 * 4 + 2] = h2(q.z);
        xv[r8 * 4 + 3] = h2(q.w);
    }

    _Float16* orow = xg + (rowbase + tid) * NG;

    // ---- g-loop: 12 groups of 8 gates; W broadcast from LDS ----
    for (int gg = 0; gg < 12; ++gg) {
        float accs[8];
#pragma unroll
        for (int u = 0; u < 8; ++u) {
            const int g = gg * 8 + u;
            const uint4* wp = reinterpret_cast<const uint4*>(&wt[g * DD]);
            float a0 = bt[g], a1 = 0.f;
#pragma unroll
            for (int k8 = 0; k8 < 8; ++k8) {
                uint4 q = wp[k8];                        // broadcast read
                a0 = fdot2(xv[k8 * 4 + 0], h2(q.x), a0);
                a1 = fdot2(xv[k8 * 4 + 1], h2(q.y), a1);
                a0 = fdot2(xv[k8 * 4 + 2], h2(q.z), a0);
                a1 = fdot2(xv[k8 * 4 + 3], h2(q.w), a1);
            }
            accs[u] = a0 + a1;
        }
        half2v p0{(_Float16)accs[0], (_Float16)accs[1]};
        half2v p1{(_Float16)accs[2], (_Float16)accs[3]};
        half2v p2{(_Float16)accs[4], (_Float16)accs[5]};
        half2v p3{(_Float16)accs[6], (_Float16)accs[7]};
        uint4 st{__builtin_bit_cast(unsigned int, p0),
                 __builtin_bit_cast(unsigned int, p1),
                 __builtin_bit_cast(unsigned int, p2),
                 __builtin_bit_cast(unsigned int, p3)};
        *reinterpret_cast<uint4*>(&orow[gg * 8]) = st;
    }
}

// =====================================================================
// Kernel 2: recurrence, full-row dots. One wave per batch; lane owns
// h = lane&31 and computes the COMPLETE 32-j dot for all 3 gates
// (48 fdot2/iter, both halves redundant). NO cross-lane ops in the
// loop: the only DS is the h write -> barrier -> broadcast read.
// waves_per_eu(1,1): full VGPR budget, weights resident (r7-proven).
// =====================================================================
__global__ __launch_bounds__(64)
__attribute__((amdgpu_waves_per_eu(1, 1)))
void gru_rec(
    const _Float16* __restrict__ xg,
    const float* __restrict__ Whh,
    const float* __restrict__ bhh,
    const float* __restrict__ Wfc,
    const float* __restrict__ bfc,
    float* __restrict__ out)
{
    __shared__ __align__(16) _Float16 hs16[HH];

    const int b    = blockIdx.x;
    const int lane = threadIdx.x;
    const int h    = lane & 31;

    // ---- full W_hh rows (r,z,n): 48 packed half2 regs ----
    half2v ur2[16], uz2[16], un2[16];
    {
        const float4* pr = reinterpret_cast<const float4*>(Whh + (0*HH + h)*HH);
        const float4* pz = reinterpret_cast<const float4*>(Whh + (1*HH + h)*HH);
        const float4* pn = reinterpret_cast<const float4*>(Whh + (2*HH + h)*HH);
#pragma unroll
        for (int k = 0; k < 8; ++k) {
            float4 a = pr[k];
            ur2[2*k]   = half2v{(_Float16)a.x, (_Float16)a.y};
            ur2[2*k+1] = half2v{(_Float16)a.z, (_Float16)a.w};
            float4 c = pz[k];
            uz2[2*k]   = half2v{(_Float16)c.x, (_Float16)c.y};
            uz2[2*k+1] = half2v{(_Float16)c.z, (_Float16)c.w};
            float4 e = pn[k];
            un2[2*k]   = half2v{(_Float16)e.x, (_Float16)e.y};
            un2[2*k+1] = half2v{(_Float16)e.z, (_Float16)e.w};
        }
    }

    const float cr  = bhh[h];
    const float cz  = bhh[HH + h];
    const float cn  = bhh[2*HH + h];
    const float wfc = Wfc[h];
    const float bf0 = bfc[0];

    const _Float16* xb = xg + (size_t)b * TS * NG;

    // 3-deep rotating prefetch of (xr,xz,xn) for this lane's h
    _Float16 xra = xb[0*NG + h],        xrb = xb[1*NG + h],        xrc = xb[2*NG + h];
    _Float16 xza = xb[0*NG + HH + h],   xzb = xb[1*NG + HH + h],   xzc = xb[2*NG + HH + h];
    _Float16 xna = xb[0*NG + 2*HH + h], xnb = xb[1*NG + 2*HH + h], xnc = xb[2*NG + 2*HH + h];

    float h_own = 0.f;
    half2v hv2[16];
#pragma unroll
    for (int k = 0; k < 16; ++k) hv2[k] = half2v{(_Float16)0.0f, (_Float16)0.0f};

    for (int t = 0; t < TS; ++t) {
        float xrv = (float)xra;
        float xzv = (float)xza;
        float xnv = (float)xna;
        xra = xrb; xrb = xrc;
        xza = xzb; xzb = xzc;
        xna = xnb; xnb = xnc;
        int tf = t + 3; if (tf > TS - 1) tf = TS - 1;
        xrc = xb[tf*NG + h];
        xzc = xb[tf*NG + HH + h];
        xnc = xb[tf*NG + 2*HH + h];

        // ---- full dots: 48 fdot2, 2 accumulator chains per gate ----
        float gr0 = 0.f, gr1 = 0.f, gz0 = 0.f, gz1 = 0.f, gn0 = 0.f, gn1 = 0.f;
#pragma unroll
        for (int k = 0; k < 8; ++k) {
            gr0 = fdot2(ur2[2*k  ], hv2[2*k  ], gr0);
            gr1 = fdot2(ur2[2*k+1], hv2[2*k+1], gr1);
            gz0 = fdot2(uz2[2*k  ], hv2[2*k  ], gz0);
            gz1 = fdot2(uz2[2*k+1], hv2[2*k+1], gz1);
            gn0 = fdot2(un2[2*k  ], hv2[2*k  ], gn0);
            gn1 = fdot2(un2[2*k+1], hv2[2*k+1], gn1);
        }
        float gr = gr0 + gr1;
        float gz = gz0 + gz1;
        float gn = gn0 + gn1;

        // ---- gates (no cross-lane needed) ----
        float r = fast_sigmoid(xrv + cr + gr);
        float z = fast_sigmoid(xzv + cz + gz);
        float npre = xnv + r * (gn + cn);
        npre = fminf(fmaxf(npre, -30.f), 30.f);
        float e2 = __expf(-2.f * npre);
        float n = (1.f - e2) * __builtin_amdgcn_rcpf(1.f + e2);
        h_own = n + z * (h_own - n);

        // ---- broadcast h (fp16): write + barrier + broadcast read ----
        hs16[h] = (_Float16)h_own;   // both halves write identical value
        __builtin_amdgcn_wave_barrier();
        {
            const uint4* hp = reinterpret_cast<const uint4*>(&hs16[0]);
            uint4 q0 = hp[0];
            uint4 q1 = hp[1];
            uint4 q2 = hp[2];
            uint4 q3 = hp[3];
            hv2[ 0] = h2(q0.x); hv2[ 1] = h2(q0.y); hv2[ 2] = h2(q0.z); hv2[ 3] = h2(q0.w);
            hv2[ 4] = h2(q1.x); hv2[ 5] = h2(q1.y); hv2[ 6] = h2(q1.z); hv2[ 7] = h2(q1.w);
            hv2[ 8] = h2(q2.x); hv2[ 9] = h2(q2.y); hv2[10] = h2(q2.z); hv2[11] = h2(q2.w);
            hv2[12] = h2(q3.x); hv2[13] = h2(q3.y); hv2[14] = h2(q3.z); hv2[15] = h2(q3.w);
        }
    }

    // final fc: out[b] = dot(h, W_fc) + b_fc (each h counted twice -> x0.5)
    float v = h_own * wfc;
#pragma unroll
    for (int off = 32; off >= 1; off >>= 1) v += __shfl_xor(v, off);
    if (lane == 0) out[b] = 0.5f * v + bf0;
}

// =====================================================================
// Fallback (round-2 kernel, known-passing) if ws is too small.
// =====================================================================
__global__ __launch_bounds__(64, 1) void gru_fused_fb(
    const float* __restrict__ x,
    const float* __restrict__ Wih,
    const float* __restrict__ Whh,
    const float* __restrict__ bih,
    const float* __restrict__ bhh,
    const float* __restrict__ Wfc,
    const float* __restrict__ bfc,
    float* __restrict__ out)
{
    __shared__ __align__(16) _Float16 xs16[4][DD];
    __shared__ __align__(16) _Float16 hs16[HH];

    const int b    = blockIdx.x;
    const int lane = threadIdx.x;
    const int s    = lane >> 5;
    const int h    = lane & 31;

    half2v wr2[16], wz2[16], wn2[16];
    {
        const float4* pr = reinterpret_cast<const float4*>(Wih + (0*HH + h)*DD + s*32);
        const float4* pz = reinterpret_cast<const float4*>(Wih + (1*HH + h)*DD + s*32);
        const float4* pn = reinterpret_cast<const float4*>(Wih + (2*HH + h)*DD + s*32);
#pragma unroll
        for (int k = 0; k < 8; ++k) {
            float4 a = pr[k];
            wr2[2*k]   = half2v{(_Float16)a.x, (_Float16)a.y};
            wr2[2*k+1] = half2v{(_Float16)a.z, (_Float16)a.w};
            float4 c = pz[k];
            wz2[2*k]   = half2v{(_Float16)c.x, (_Float16)c.y};
            wz2[2*k+1] = half2v{(_Float16)c.z, (_Float16)c.w};
            float4 e = pn[k];
            wn2[2*k]   = half2v{(_Float16)e.x, (_Float16)e.y};
            wn2[2*k+1] = half2v{(_Float16)e.z, (_Float16)e.w};
        }
    }
    half2v ur2[8], uz2[8], un2[8];
    {
        const float4* pr = reinterpret_cast<const float4*>(Whh + (0*HH + h)*HH + s*16);
        const float4* pz = reinterpret_cast<const float4*>(Whh + (1*HH + h)*HH + s*16);
        const float4* pn = reinterpret_cast<const float4*>(Whh + (2*HH + h)*HH + s*16);
#pragma unroll
        for (int k = 0; k < 4; ++k) {
            float4 a = pr[k];
            ur2[2*k]   = half2v{(_Float16)a.x, (_Float16)a.y};
            ur2[2*k+1] = half2v{(_Float16)a.z, (_Float16)a.w};
            float4 c = pz[k];
            uz2[2*k]   = half2v{(_Float16)c.x, (_Float16)c.y};
            uz2[2*k+1] = half2v{(_Float16)c.z, (_Float16)c.w};
            float4 e = pn[k];
            un2[2*k]   = half2v{(_Float16)e.x, (_Float16)e.y};
            un2[2*k+1] = half2v{(_Float16)e.z, (_Float16)e.w};
        }
    }

    const float br  = bih[h]        + bhh[h];
    const float bz  = bih[HH + h]   + bhh[HH + h];
    const float bxn = bih[2*HH + h];
    const float bhn = bhh[2*HH + h];
    const float wfc = Wfc[h];
    const float bf0 = bfc[0];

    const float* xrow = x + (size_t)b * TS * DD;

    float p0 = xrow[0*DD + lane];
    float p1 = xrow[1*DD + lane];
    float p2 = xrow[2*DD + lane];
    float ra = xrow[3*DD + lane];
    float rb = xrow[4*DD + lane];
    float rc = xrow[5*DD + lane];
    xs16[0][lane] = (_Float16)p0;
    xs16[1][lane] = (_Float16)p1;
    xs16[2][lane] = (_Float16)p2;
    __builtin_amdgcn_wave_barrier();

    float h_own = 0.0f;
    half2v hv2[8];
#pragma unroll
    for (int k = 0; k < 8; ++k) hv2[k] = half2v{(_Float16)0.0f, (_Float16)0.0f};

    float ar, az, an;
    {
        const uint4* xp = reinterpret_cast<const uint4*>(&xs16[0][s * 32]);
        ar = 0.f; az = 0.f; an = 0.f;
#pragma unroll
        for (int k = 0; k < 4; ++k) {
            uint4 q = xp[k];
            half2v v0 = h2(q.x), v1 = h2(q.y), v2 = h2(q.z), v3 = h2(q.w);
            ar = fdot2(wr2[4*k  ], v0, ar);  az = fdot2(wz2[4*k  ], v0, az);  an = fdot2(wn2[4*k  ], v0, an);
            ar = fdot2(wr2[4*k+1], v1, ar);  az = fdot2(wz2[4*k+1], v1, az);  an = fdot2(wn2[4*k+1], v1, an);
            ar = fdot2(wr2[4*k+2], v2, ar);  az = fdot2(wz2[4*k+2], v2, az);  an = fdot2(wn2[4*k+2], v2, an);
            ar = fdot2(wr2[4*k+3], v3, ar);  az = fdot2(wz2[4*k+3], v3, az);  an = fdot2(wn2[4*k+3], v3, an);
        }
    }

    for (int t = 0; t < TS; ++t) {
        xs16[(t + 3) & 3][lane] = (_Float16)ra;
        ra = rb; rb = rc;
        int tf = t + 6; if (tf > TS - 1) tf = TS - 1;
        rc = xrow[tf * DD + lane];

        float gr = 0.f, gz = 0.f, gn = 0.f;
#pragma unroll
        for (int k = 0; k < 8; ++k) {
            gr = fdot2(ur2[k], hv2[k], gr);
            gz = fdot2(uz2[k], hv2[k], gz);
            gn = fdot2(un2[k], hv2[k], gn);
        }

        float tr = ar + gr;  tr += __shfl_xor(tr, 32);
        float tz = az + gz;  tz += __shfl_xor(tz, 32);
        float txn = an + __shfl_xor(an, 32);
        float tgn = gn + __shfl_xor(gn, 32);

        float r = fast_sigmoid(tr + br);
        float z = fast_sigmoid(tz + bz);
        float npre = txn + bxn + r * (tgn + bhn);
        npre = fminf(fmaxf(npre, -30.f), 30.f);
        float e2 = __expf(-2.f * npre);
        float n = (1.f - e2) * __builtin_amdgcn_rcpf(1.f + e2);
        h_own = n + z * (h_own - n);

        hs16[h] = (_Float16)h_own;
        __builtin_amdgcn_wave_barrier();
        {
            const uint4* hp = reinterpret_cast<const uint4*>(&hs16[s * 16]);
            uint4 q0 = hp[0];
            uint4 q1 = hp[1];
            hv2[0] = h2(q0.x);
            hv2[1] = h2(q0.y);
            hv2[2] = h2(q0.z);
            hv2[3] = h2(q0.w);
            hv2[4] = h2(q1.x);
            hv2[5] = h2(q1.y);
            hv2[6] = h2(q1.z);
            hv2[7] = h2(q1.w);
        }

        if (t + 1 < TS) {
            const uint4* xp = reinterpret_cast<const uint4*>(&xs16[(t + 1) & 3][s * 32]);
            ar = 0.f; az = 0.f; an = 0.f;
#pragma unroll
            for (int k = 0; k < 4; ++k) {
                uint4 q = xp[k];
                half2v v0 = h2(q.x), v1 = h2(q.y), v2 = h2(q.z), v3 = h2(q.w);
                ar = fdot2(wr2[4*k  ], v0, ar);  az = fdot2(wz2[4*k  ], v0, az);  an = fdot2(wn2[4*k  ], v0, an);
                ar = fdot2(wr2[4*k+1], v1, ar);  az = fdot2(wz2[4*k+1], v1, az);  an = fdot2(wn2[4*k+1], v1, an);
                ar = fdot2(wr2[4*k+2], v2, ar);  az = fdot2(wz2[4*k+2], v2, az);  an = fdot2(wn2[4*k+2], v2, an);
                ar = fdot2(wr2[4*k+3], v3, ar);  az = fdot2(wz2[4*k+3], v3, az);  an = fdot2(wn2[4*k+3], v3, an);
            }
        }
    }

    float v = h_own * wfc;
#pragma unroll
    for (int off = 32; off >= 1; off >>= 1) v += __shfl_xor(v, off);
    if (lane == 0) out[b] = 0.5f * v + bf0;
}

extern "C" void kernel_launch(void* const* d_in, const int* in_sizes, int n_in,
                              void* d_out, int out_size, void* d_ws, size_t ws_size,
                              hipStream_t stream) {
    const float* x    = (const float*)d_in[0];
    const float* Wih  = (const float*)d_in[1];
    const float* Whh  = (const float*)d_in[2];
    const float* bih  = (const float*)d_in[3];
    const float* bhh  = (const float*)d_in[4];
    const float* Wfc  = (const float*)d_in[5];
    const float* bfc  = (const float*)d_in[6];
    float* out = (float*)d_out;

    const int B = in_sizes[0] / (TS * DD);   // 1024
    const int M = B * TS;                    // 524288 rows
    const size_t need = (size_t)M * NG * sizeof(_Float16);  // 100.7 MB

    if (ws_size >= need && (M % ROWS) == 0) {
        _Float16* xg = (_Float16*)d_ws;
        xg_par<<<dim3(M / ROWS), dim3(256), 0, stream>>>(x, Wih, bih, xg);
        gru_rec<<<dim3(B), dim3(64), 0, stream>>>(xg, Whh, bhh, Wfc, bfc, out);
    } else {
        gru_fused_fb<<<dim3(B), dim3(64), 0, stream>>>(x, Wih, Whh, bih, bhh, Wfc, bfc, out);
    }
}

// Round 10
// 185.266 us; speedup vs baseline: 1.5944x; 1.3005x over previous
//
#include <hip/hip_runtime.h>

#define TS 512  // timesteps
#define DD 64   // input dim
#define HH 32   // hidden dim

typedef _Float16 half2v __attribute__((ext_vector_type(2)));

__device__ __forceinline__ float fdot2(half2v a, half2v b, float c) {
#if __has_builtin(__builtin_amdgcn_fdot2)
    return __builtin_amdgcn_fdot2(a, b, c, false);
#else
    return fmaf((float)a[0], (float)b[0], fmaf((float)a[1], (float)b[1], c));
#endif
}

__device__ __forceinline__ float fast_sigmoid(float a) {
    return __builtin_amdgcn_rcpf(1.0f + __expf(-a));
}

__device__ __forceinline__ half2v h2(unsigned int u) {
    return __builtin_bit_cast(half2v, u);
}

// One wave (64 lanes) per batch element.  lane = s*32 + h.
// EXACT round-2 structure (best measured total: 190us, absmax 0.0078),
// with ONE change: amdgpu_waves_per_eu(1,1) so the register allocator
// gets the full 1-wave/EU VGPR budget (512) and keeps the 72 packed
// weight registers resident instead of spill/reloading them every
// iteration (r2 ran at VGPR=84 -> in-loop reloads; r7 proved this
// attribute lifts the budget: VGPR 32->132 on gru_rec).
__global__ __launch_bounds__(64)
__attribute__((amdgpu_waves_per_eu(1, 1)))
void gru_fused(
    const float* __restrict__ x,
    const float* __restrict__ Wih,
    const float* __restrict__ Whh,
    const float* __restrict__ bih,
    const float* __restrict__ bhh,
    const float* __restrict__ Wfc,
    const float* __restrict__ bfc,
    float* __restrict__ out)
{
    __shared__ __align__(16) _Float16 xs16[4][DD];  // rotating x staging (fp16)
    __shared__ __align__(16) _Float16 hs16[HH];     // h broadcast (fp16)

    const int b    = blockIdx.x;
    const int lane = threadIdx.x;
    const int s    = lane >> 5;   // 0/1: which half of the dot
    const int h    = lane & 31;   // hidden index owned by this lane

    // ---- W_ih rows (r,z,n), this lane's d-half: 48 packed regs ----
    half2v wr2[16], wz2[16], wn2[16];
    {
        const float4* pr = reinterpret_cast<const float4*>(Wih + (0 * HH + h) * DD + s * 32);
        const float4* pz = reinterpret_cast<const float4*>(Wih + (1 * HH + h) * DD + s * 32);
        const float4* pn = reinterpret_cast<const float4*>(Wih + (2 * HH + h) * DD + s * 32);
#pragma unroll
        for (int k = 0; k < 8; ++k) {
            float4 a = pr[k];
            wr2[2*k]   = half2v{(_Float16)a.x, (_Float16)a.y};
            wr2[2*k+1] = half2v{(_Float16)a.z, (_Float16)a.w};
            float4 c = pz[k];
            wz2[2*k]   = half2v{(_Float16)c.x, (_Float16)c.y};
            wz2[2*k+1] = half2v{(_Float16)c.z, (_Float16)c.w};
            float4 e = pn[k];
            wn2[2*k]   = half2v{(_Float16)e.x, (_Float16)e.y};
            wn2[2*k+1] = half2v{(_Float16)e.z, (_Float16)e.w};
        }
    }
    // ---- W_hh rows, this lane's j-half: 24 packed regs ----
    half2v ur2[8], uz2[8], un2[8];
    {
        const float4* pr = reinterpret_cast<const float4*>(Whh + (0 * HH + h) * HH + s * 16);
        const float4* pz = reinterpret_cast<const float4*>(Whh + (1 * HH + h) * HH + s * 16);
        const float4* pn = reinterpret_cast<const float4*>(Whh + (2 * HH + h) * HH + s * 16);
#pragma unroll
        for (int k = 0; k < 4; ++k) {
            float4 a = pr[k];
            ur2[2*k]   = half2v{(_Float16)a.x, (_Float16)a.y};
            ur2[2*k+1] = half2v{(_Float16)a.z, (_Float16)a.w};
            float4 c = pz[k];
            uz2[2*k]   = half2v{(_Float16)c.x, (_Float16)c.y};
            uz2[2*k+1] = half2v{(_Float16)c.z, (_Float16)c.w};
            float4 e = pn[k];
            un2[2*k]   = half2v{(_Float16)e.x, (_Float16)e.y};
            un2[2*k+1] = half2v{(_Float16)e.z, (_Float16)e.w};
        }
    }

    const float br  = bih[h]          + bhh[h];
    const float bz  = bih[HH + h]     + bhh[HH + h];
    const float bxn = bih[2 * HH + h];
    const float bhn = bhh[2 * HH + h];
    const float wfc = Wfc[h];
    const float bf0 = bfc[0];

    const float* xrow = x + (size_t)b * TS * DD;

    // ---- prologue: stage slots 0..2, keep 3 loads in flight ----
    float p0 = xrow[0 * DD + lane];
    float p1 = xrow[1 * DD + lane];
    float p2 = xrow[2 * DD + lane];
    float ra = xrow[3 * DD + lane];
    float rb = xrow[4 * DD + lane];
    float rc = xrow[5 * DD + lane];
    xs16[0][lane] = (_Float16)p0;
    xs16[1][lane] = (_Float16)p1;
    xs16[2][lane] = (_Float16)p2;
    __builtin_amdgcn_wave_barrier();

    float h_own = 0.0f;
    half2v hv2[8];
#pragma unroll
    for (int k = 0; k < 8; ++k) hv2[k] = half2v{(_Float16)0.0f, (_Float16)0.0f};

    // xg partials for t=0 (x already staged)
    float ar, az, an;
    {
        const uint4* xp = reinterpret_cast<const uint4*>(&xs16[0][s * 32]);
        ar = 0.f; az = 0.f; an = 0.f;
#pragma unroll
        for (int k = 0; k < 4; ++k) {
            uint4 q = xp[k];
            half2v v0 = h2(q.x), v1 = h2(q.y), v2 = h2(q.z), v3 = h2(q.w);
            ar = fdot2(wr2[4*k  ], v0, ar);
            az = fdot2(wz2[4*k  ], v0, az);
            an = fdot2(wn2[4*k  ], v0, an);
            ar = fdot2(wr2[4*k+1], v1, ar);
            az = fdot2(wz2[4*k+1], v1, az);
            an = fdot2(wn2[4*k+1], v1, an);
            ar = fdot2(wr2[4*k+2], v2, ar);
            az = fdot2(wz2[4*k+2], v2, az);
            an = fdot2(wn2[4*k+2], v2, an);
            ar = fdot2(wr2[4*k+3], v3, ar);
            az = fdot2(wz2[4*k+3], v3, az);
            an = fdot2(wn2[4*k+3], v3, an);
        }
    }

    for (int t = 0; t < TS; ++t) {
        // stage step t+3 (its load was issued 3 iterations ago)
        xs16[(t + 3) & 3][lane] = (_Float16)ra;
        ra = rb; rb = rc;
        int tf = t + 6; if (tf > TS - 1) tf = TS - 1;   // harmless tail re-read
        rc = xrow[tf * DD + lane];

        // ---- gh partial dots (this lane's 16 of 32 j's) ----
        float gr = 0.f, gz = 0.f, gn = 0.f;
#pragma unroll
        for (int k = 0; k < 8; ++k) {
            gr = fdot2(ur2[k], hv2[k], gr);
            gz = fdot2(uz2[k], hv2[k], gz);
            gn = fdot2(un2[k], hv2[k], gn);
        }

        // ---- combine halves (3 independent shfls; latencies overlap) ----
        float tr = ar + gr;  tr += __shfl_xor(tr, 32);
        float tz = az + gz;  tz += __shfl_xor(tz, 32);
        float txn = an + __shfl_xor(an, 32);
        float tgn = gn + __shfl_xor(gn, 32);

        // ---- gates (redundant in both halves; identical results) ----
        float r = fast_sigmoid(tr + br);
        float z = fast_sigmoid(tz + bz);
        float npre = txn + bxn + r * (tgn + bhn);
        npre = fminf(fmaxf(npre, -30.f), 30.f);
        float e2 = __expf(-2.f * npre);
        float n = (1.f - e2) * __builtin_amdgcn_rcpf(1.f + e2);
        h_own = n + z * (h_own - n);

        // ---- broadcast h (fp16) — wave-synchronous, block == 1 wave ----
        hs16[h] = (_Float16)h_own;
        __builtin_amdgcn_wave_barrier();
        {
            const uint4* hp = reinterpret_cast<const uint4*>(&hs16[s * 16]);
            uint4 q0 = hp[0];
            uint4 q1 = hp[1];
            hv2[0] = h2(q0.x);
            hv2[1] = h2(q0.y);
            hv2[2] = h2(q0.z);
            hv2[3] = h2(q0.w);
            hv2[4] = h2(q1.x);
            hv2[5] = h2(q1.y);
            hv2[6] = h2(q1.z);
            hv2[7] = h2(q1.w);
        }

        // ---- xg partials for step t+1 (independent; hides h-read latency) ----
        if (t + 1 < TS) {
            const uint4* xp = reinterpret_cast<const uint4*>(&xs16[(t + 1) & 3][s * 32]);
            ar = 0.f; az = 0.f; an = 0.f;
#pragma unroll
            for (int k = 0; k < 4; ++k) {
                uint4 q = xp[k];
                half2v v0 = h2(q.x), v1 = h2(q.y), v2 = h2(q.z), v3 = h2(q.w);
                ar = fdot2(wr2[4*k  ], v0, ar);
                az = fdot2(wz2[4*k  ], v0, az);
                an = fdot2(wn2[4*k  ], v0, an);
                ar = fdot2(wr2[4*k+1], v1, ar);
                az = fdot2(wz2[4*k+1], v1, az);
                an = fdot2(wn2[4*k+1], v1, an);
                ar = fdot2(wr2[4*k+2], v2, ar);
                az = fdot2(wz2[4*k+2], v2, az);
                an = fdot2(wn2[4*k+2], v2, an);
                ar = fdot2(wr2[4*k+3], v3, ar);
                az = fdot2(wz2[4*k+3], v3, az);
                an = fdot2(wn2[4*k+3], v3, an);
            }
        }
    }

    // ---- final fc: out[b] = dot(h, W_fc) + b_fc (each h counted twice) ----
    float v = h_own * wfc;
#pragma unroll
    for (int off = 32; off >= 1; off >>= 1) v += __shfl_xor(v, off);
    if (lane == 0) out[b] = 0.5f * v + bf0;
}

extern "C" void kernel_launch(void* const* d_in, const int* in_sizes, int n_in,
                              void* d_out, int out_size, void* d_ws, size_t ws_size,
                              hipStream_t stream) {
    const float* x    = (const float*)d_in[0];
    const float* Wih  = (const float*)d_in[1];
    const float* Whh  = (const float*)d_in[2];
    const float* bih  = (const float*)d_in[3];
    const float* bhh  = (const float*)d_in[4];
    const float* Wfc  = (const float*)d_in[5];
    const float* bfc  = (const float*)d_in[6];
    float* out = (float*)d_out;

    const int B = in_sizes[0] / (TS * DD);   // 1024
    gru_fused<<<dim3(B), dim3(64), 0, stream>>>(x, Wih, Whh, bih, bhh, Wfc, bfc, out);
}